// Round 17
// baseline (42.216 us; speedup 1.0000x reference)
//
#include <hip/hip_runtime.h>
#include <stdint.h>

#define NPIX 4096
#define CIN  256
#define CR   64
#define COUT 512
#define NB   8
#define CG   256     // icn guard floats each side (also covers feat_h head)
#define FT   128     // feat_h tail guard (floats; covers +4 px overhang)

typedef _Float16 half8 __attribute__((ext_vector_type(8)));
typedef _Float16 half4 __attribute__((ext_vector_type(4)));
typedef _Float16 half2v __attribute__((ext_vector_type(2)));
typedef float f32x4 __attribute__((ext_vector_type(4)));

// 8-lane sum (groups aligned to 8): quad_perm xor1, xor2, then row_half_mirror.
__device__ __forceinline__ float dpp8_sum(float d) {
  int y;
  y = __builtin_amdgcn_update_dpp(0, __float_as_int(d), 0xB1, 0xF, 0xF, true);
  d += __int_as_float(y);
  y = __builtin_amdgcn_update_dpp(0, __float_as_int(d), 0x4E, 0xF, 0xF, true);
  d += __int_as_float(y);
  y = __builtin_amdgcn_update_dpp(0, __float_as_int(d), 0x141, 0xF, 0xF, true);
  d += __int_as_float(y);
  return d;
}

// ---------------------------------------------------------------------------
// K0: pack w_reduce into hi/lo fp16 A-fragments (k1 MFMA), wp into fp16
// A-fragments (k23 phase B), zero guard zones. (unchanged from r15)
// ---------------------------------------------------------------------------
__global__ __launch_bounds__(256) void k0_prep(
    const float* __restrict__ wr, const float* __restrict__ wp,
    _Float16* __restrict__ wrAh, _Float16* __restrict__ wrAl,
    _Float16* __restrict__ wpH,
    float* __restrict__ icnG, float* __restrict__ featTail)
{
  const int tid = blockIdx.x * 256 + threadIdx.x;
  if (tid < 16384) {                          // wr[64][256] -> hi/lo A-frags
    const int j = tid & 7, l = (tid >> 3) & 63;
    const int kt = (tid >> 9) & 7, mt = tid >> 12;
    const int m = mt * 16 + (l & 15);
    const int k = kt * 32 + (l >> 4) * 8 + j;
    const float v = wr[m * CIN + k];
    const _Float16 h = (_Float16)v;
    wrAh[tid] = h;
    wrAl[tid] = (_Float16)(v - (float)h);
  } else if (tid < 16384 + COUT * CR) {       // wp[512][64] -> A-frags f16
    const int fi = tid - 16384;
    const int j = fi & 7, l = (fi >> 3) & 63;
    const int kt = (fi >> 9) & 1, ot = (fi >> 10) & 3, g = fi >> 12;
    const int o = g * 64 + ot * 16 + (l & 15);
    const int k = kt * 32 + (l >> 4) * 8 + j;
    wpH[fi] = (_Float16)wp[o * CR + k];
  } else {
    const int gi = tid - (16384 + COUT * CR);
    if (gi < CG)               icnG[gi] = 0.f;                         // head
    else if (gi < 2 * CG)      icnG[CG + NB * NPIX + (gi - CG)] = 0.f; // tail
    else if (gi < 2 * CG + FT) featTail[gi - 2 * CG] = 0.f;            // feat tail
  }
}

// ---------------------------------------------------------------------------
// K1 (MFMA): feat_h[b,px,ch] (f16, px-major) = sum_k wr[c][k]*x[b,k,px];
// icn (f32) = rsqrt(max(sum_c feat^2, 1e-16)). (unchanged from r15)
// ---------------------------------------------------------------------------
__global__ __launch_bounds__(512) void k1_reduce(
    const float* __restrict__ x,
    const _Float16* __restrict__ wrAh, const _Float16* __restrict__ wrAl,
    _Float16* __restrict__ feat_h, float* __restrict__ icn)
{
  const int blk = blockIdx.x;             // 512 = b(3b) | seg(6b)
  const int b = blk >> 6, seg = blk & 63;
  const int t = threadIdx.x, lane = t & 63;
  const int g = __builtin_amdgcn_readfirstlane((int)t >> 6);  // 0..7
  const int nt = g & 3, mth = g >> 2;
  const int col = lane & 15, krow = lane >> 4;

  const float* xb = x + (size_t)b * CIN * NPIX + seg * 64 + nt * 16 + col;

  f32x4 c0 = {0.f, 0.f, 0.f, 0.f};
  f32x4 c1 = {0.f, 0.f, 0.f, 0.f};

#pragma unroll
  for (int kt = 0; kt < 8; ++kt) {
    half8 Bh, Bl;
    const float* xk = xb + (size_t)(kt * 32 + krow * 8) * NPIX;
#pragma unroll
    for (int j = 0; j < 8; ++j) {
      const float v = xk[(size_t)j * NPIX];
      const _Float16 h = (_Float16)v;
      Bh[j] = h;
      Bl[j] = (_Float16)(v - (float)h);
    }
    const int fi0 = ((mth * 2 + 0) * 8 + kt) * 512 + lane * 8;
    const int fi1 = ((mth * 2 + 1) * 8 + kt) * 512 + lane * 8;
    const half8 Ah0 = *(const half8*)(wrAh + fi0);
    const half8 Al0 = *(const half8*)(wrAl + fi0);
    const half8 Ah1 = *(const half8*)(wrAh + fi1);
    const half8 Al1 = *(const half8*)(wrAl + fi1);
    c0 = __builtin_amdgcn_mfma_f32_16x16x32_f16(Ah0, Bh, c0, 0, 0, 0);
    c0 = __builtin_amdgcn_mfma_f32_16x16x32_f16(Ah0, Bl, c0, 0, 0, 0);
    c0 = __builtin_amdgcn_mfma_f32_16x16x32_f16(Al0, Bh, c0, 0, 0, 0);
    c1 = __builtin_amdgcn_mfma_f32_16x16x32_f16(Ah1, Bh, c1, 0, 0, 0);
    c1 = __builtin_amdgcn_mfma_f32_16x16x32_f16(Ah1, Bl, c1, 0, 0, 0);
    c1 = __builtin_amdgcn_mfma_f32_16x16x32_f16(Al1, Bh, c1, 0, 0, 0);
  }

  // C layout (HW-verified): col = lane&15, row = krow*4 + r (consecutive ch)
  const int px = seg * 64 + nt * 16 + col;
  _Float16* fb = feat_h + ((size_t)b * NPIX + px) * 64;
  const int ch0 = mth * 32 + krow * 4;
  half4 v0, v1;
  float p = 0.f;
#pragma unroll
  for (int r = 0; r < 4; ++r) {
    v0[r] = (_Float16)c0[r];
    v1[r] = (_Float16)c1[r];
    p = fmaf(c0[r], c0[r], p);
    p = fmaf(c1[r], c1[r], p);
  }
  *(half4*)(fb + ch0) = v0;
  *(half4*)(fb + ch0 + 16) = v1;

  p += __shfl_xor(p, 16);
  p += __shfl_xor(p, 32);

  __shared__ float cn[8][16];
  if (lane < 16) cn[g][lane] = p;
  __syncthreads();
  if (t < 64) {
    const int nt2 = t >> 4, c16 = t & 15;
    const float ss = cn[nt2][c16] + cn[nt2 + 4][c16];
    icn[b * NPIX + seg * 64 + t] = rsqrtf(fmaxf(ss, 1e-16f));
  }
}

// ---------------------------------------------------------------------------
// K23: fused attention+proj, TWO center rows per block (h0=2*hh, h1=h0+1).
// 256 blocks x 1024 thr (16 waves); waves 0-7 own row h0, waves 8-15 row h1
// (wave-uniform split). Halo union = 8 staged rows per 2 center rows (vs 14
// for separate blocks): -43% staging, 10 barriers vs 16. XCD map b=blk&7
// (256 blocks = 1 per CU, 4 waves/SIMD).
//
// Per ar row: LOAD (576 x h8, contiguous) early; wave computes its 7 dx only
// if ar in [rc-3, rc+3] (uniform branch); WRITE after compute; one barrier.
// Inner loop identical to r15 (ds_read_b128, 4x fdot2, dpp8, sim=d*icnc*icnk,
// one-pass softmax, pk_fma f16 dual accumulators).
// Phase B: per-row corrH[2][.] XOR-swizzled; A-frags hoisted to regs before
// the barrier; wave wv -> row wv>>3, outs (wv&7)*64..+64.
// ---------------------------------------------------------------------------
__global__ __launch_bounds__(1024, 4) void k23_fused(
    const _Float16* __restrict__ feat_h, const float* __restrict__ icn,
    const _Float16* __restrict__ wpH, float* __restrict__ out)
{
  const int blk = blockIdx.x;          // 256
  const int b = blk & 7, hh = blk >> 3;
  const int h0 = hh * 2;
  const int t = threadIdx.x;
  const int lane = t & 63;
  const int wv = __builtin_amdgcn_readfirstlane((int)t >> 6);  // 0..15
  const int half = wv >> 3;            // wave-uniform: 0 -> row h0, 1 -> h1
  const int tl = t & 511;
  const int w = tl >> 3;               // px col 0..63
  const int cb = (tl & 7) * 8;         // channel base for this lane
  const int rc = h0 + half;            // this thread's center row
  const int px = rc * 64 + w;
  const int gpx = b * NPIX + px;

  const float* cnb = icn + b * NPIX;

  __shared__ __align__(16) _Float16 fs[2][72][72];   // 20736 B
  __shared__ float cnS[2][80];                       // 640 B
  __shared__ __align__(16) _Float16 corrH[2][4096];  // 16384 B

  half8 rS0;
  float ricn = 0.f;

  auto LOAD = [&](int ar) {
    const long rowb = ((long)b * NPIX + ar * 64 - 4) * 64;  // f16 units
    if (t < 576) rS0 = *(const half8*)(feat_h + rowb + (long)t * 8);
    if (t < 72) ricn = cnb[ar * 64 - 4 + t];
  };
  auto WRITE = [&](int bufi) {
    if (t < 576) *(half8*)&fs[bufi][t >> 3][(t & 7) * 8] = rS0;
    if (t < 72) cnS[bufi][t] = ricn;
  };

  // center features (f16, contiguous 16 B per lane)
  half2v fc2[4];
  {
    const half8 fcv = *(const half8*)(feat_h + ((size_t)b * NPIX + px) * 64 + cb);
#pragma unroll
    for (int i = 0; i < 4; ++i) { fc2[i][0] = fcv[2*i]; fc2[i][1] = fcv[2*i+1]; }
  }
  const float icnc = icn[gpx];

  half2v accA[4], accB[4];
#pragma unroll
  for (int i = 0; i < 4; ++i) {
    accA[i] = (half2v)(_Float16)0.f;
    accB[i] = (half2v)(_Float16)0.f;
  }

  const int lo_r = (rc - 3 < 0) ? 0 : rc - 3;
  const int hi_r = (rc + 3 > 63) ? 63 : rc + 3;
  float l = 7.0f * (float)(6 - (hi_r - lo_r));   // skipped rows: 7 x exp(0)

  const int blo = (h0 - 3 < 0) ? 0 : h0 - 3;
  const int bhi = (h0 + 4 > 63) ? 63 : h0 + 4;

  LOAD(blo);
  WRITE(0);
  __syncthreads();

  int buf = 0;
  for (int ar = blo; ar <= bhi; ++ar) {
    if (ar < bhi) LOAD(ar + 1);              // issue early: hides under compute
    if (ar >= lo_r && ar <= hi_r) {          // wave-uniform window check
#pragma unroll
      for (int dx = -3; dx <= 3; ++dx) {
        const int j = w + 4 + dx;
        const half8 nv = *(const half8*)&fs[buf][j][cb];
        half2v n0, n1, n2, n3;
        n0[0] = nv[0]; n0[1] = nv[1];
        n1[0] = nv[2]; n1[1] = nv[3];
        n2[0] = nv[4]; n2[1] = nv[5];
        n3[0] = nv[6]; n3[1] = nv[7];
        float d = 0.f;
        d = __builtin_amdgcn_fdot2(fc2[0], n0, d, false);
        d = __builtin_amdgcn_fdot2(fc2[1], n1, d, false);
        d = __builtin_amdgcn_fdot2(fc2[2], n2, d, false);
        d = __builtin_amdgcn_fdot2(fc2[3], n3, d, false);
        d = dpp8_sum(d);                 // 8-lane reduce, VALU-only
        const float icnk = cnS[buf][j];  // 0 on guard -> sim 0
        float sim = d * icnc * icnk;
        const bool valid = (unsigned)(w + dx) < 64u;
        sim = valid ? sim : 0.f;         // select: NaN/Inf-safe
        const float p = __expf(sim);     // sim <= 1 -> p <= e
        l += p;
        const float pv = valid ? p : 0.f;
        const _Float16 ph = (_Float16)pv;
        half2v ph2; ph2[0] = ph; ph2[1] = ph;
        if (dx & 1) {
          accA[0] = ph2 * n0 + accA[0];
          accA[1] = ph2 * n1 + accA[1];
          accA[2] = ph2 * n2 + accA[2];
          accA[3] = ph2 * n3 + accA[3];
        } else {
          accB[0] = ph2 * n0 + accB[0];
          accB[1] = ph2 * n1 + accB[1];
          accB[2] = ph2 * n2 + accB[2];
          accB[3] = ph2 * n3 + accB[3];
        }
      }
    }
    if (ar < bhi) WRITE(buf ^ 1);            // vmcnt waits here, not earlier
    __syncthreads();
    buf ^= 1;
  }

  // combine f16 partials in f32, normalize, write f16 corrH[half] (swizzled)
  {
    const float inv = __builtin_amdgcn_rcpf(l);
    half8 hv;
#pragma unroll
    for (int i = 0; i < 4; ++i) {
      const float a0 = (float)accA[i][0] + (float)accB[i][0];
      const float a1 = (float)accA[i][1] + (float)accB[i][1];
      hv[2*i]   = (_Float16)(a0 * inv);
      hv[2*i+1] = (_Float16)(a1 * inv);
    }
    const int wbyte = (w * 128 + (cb << 1)) ^ ((w & 7) << 4);
    *(half8*)((char*)&corrH[half][0] + wbyte) = hv;
  }

  // hoist phase-B A-frags (global, L2-hot) - latency hides under the barrier
  const _Float16* wA = wpH + (size_t)(wv & 7) * 4096;
  half8 Af[8];
#pragma unroll
  for (int e = 0; e < 8; ++e) Af[e] = *(const half8*)(wA + e * 512 + lane * 8);
  __syncthreads();

  // ---- Phase B: wave wv -> row (wv>>3), outs [(wv&7)*64, +64) x 64 px.
  const char* cH = (const char*)&corrH[wv >> 3][0];
  float* outb = out + ((size_t)b * COUT + (wv & 7) * 64) * NPIX
              + (h0 + (wv >> 3)) * 64;
#pragma unroll
  for (int pt = 0; pt < 4; ++pt) {
    half8 Bf0, Bf1;
    {
      const int pxl = pt * 16 + (lane & 15);
      const int sw = (pxl & 7) << 4;
      const int rowb = pxl * 128 + ((lane >> 4) << 4);
      Bf0 = *(const half8*)(cH + (rowb ^ sw));
      Bf1 = *(const half8*)(cH + ((rowb + 64) ^ sw));
    }
#pragma unroll
    for (int ot = 0; ot < 4; ++ot) {
      f32x4 c = {0.f, 0.f, 0.f, 0.f};
      c = __builtin_amdgcn_mfma_f32_16x16x32_f16(Af[ot * 2 + 0], Bf0, c, 0, 0, 0);
      c = __builtin_amdgcn_mfma_f32_16x16x32_f16(Af[ot * 2 + 1], Bf1, c, 0, 0, 0);
      float* op = outb + (size_t)(ot * 16 + ((lane >> 4) << 2)) * NPIX
                       + pt * 16 + (lane & 15);
#pragma unroll
      for (int r = 0; r < 4; ++r) op[(size_t)r * NPIX] = c[r];
    }
  }
}

// ---------------------------------------------------------------------------
extern "C" void kernel_launch(void* const* d_in, const int* in_sizes, int n_in,
                              void* d_out, int out_size, void* d_ws, size_t ws_size,
                              hipStream_t stream)
{
  const float* x  = (const float*)d_in[0];
  const float* wr = (const float*)d_in[1];
  const float* wp = (const float*)d_in[2];
  float* out = (float*)d_out;

  // ws layout (float-slots):
  //   wrAh[8192] | wrAl[8192] | wpH[16384] |
  //   [CG] icn[8*4096] [CG] | feat_h[8*4096*64 f16 = 1M float-slots] | [FT]
  float* ws = (float*)d_ws;
  _Float16* wrAh  = (_Float16*)ws;
  _Float16* wrAl  = (_Float16*)(ws + 8192);
  _Float16* wpH   = (_Float16*)(ws + 16384);
  float* icnG     = ws + 32768;             // guarded region base
  float* icn      = icnG + CG;
  _Float16* feat_h = (_Float16*)(icn + NB * NPIX + CG);
  float* featTail = (float*)(feat_h + (size_t)NB * NPIX * 64);

  hipLaunchKernelGGL(k0_prep,   dim3(195), dim3(256), 0, stream, wr, wp, wrAh, wrAl, wpH, icnG, featTail);
  hipLaunchKernelGGL(k1_reduce, dim3(512), dim3(512), 0, stream, x, wrAh, wrAl, feat_h, icn);
  hipLaunchKernelGGL(k23_fused, dim3(256), dim3(1024), 0, stream, feat_h, icn, wpH, out);
}

// Round 18
// 39.789 us; speedup vs baseline: 1.0610x; 1.0610x over previous
//
#include <hip/hip_runtime.h>
#include <stdint.h>

#define NPIX 4096
#define CIN  256
#define CR   64
#define COUT 512
#define NB   8
#define CG   256     // icn guard floats each side (also covers feat_h head)
#define FT   128     // feat_h tail guard (floats; covers +4 px overhang)

typedef _Float16 half8 __attribute__((ext_vector_type(8)));
typedef _Float16 half4 __attribute__((ext_vector_type(4)));
typedef _Float16 half2v __attribute__((ext_vector_type(2)));
typedef float f32x4 __attribute__((ext_vector_type(4)));

// 8-lane sum (groups aligned to 8): quad_perm xor1, xor2, then row_half_mirror.
__device__ __forceinline__ float dpp8_sum(float d) {
  int y;
  y = __builtin_amdgcn_update_dpp(0, __float_as_int(d), 0xB1, 0xF, 0xF, true);
  d += __int_as_float(y);
  y = __builtin_amdgcn_update_dpp(0, __float_as_int(d), 0x4E, 0xF, 0xF, true);
  d += __int_as_float(y);
  y = __builtin_amdgcn_update_dpp(0, __float_as_int(d), 0x141, 0xF, 0xF, true);
  d += __int_as_float(y);
  return d;
}

// ---------------------------------------------------------------------------
// K0: pack w_reduce into hi/lo fp16 A-fragments (k1 MFMA), wp into fp16
// A-fragments (k23 phase B), zero guard zones. (unchanged from r15)
// ---------------------------------------------------------------------------
__global__ __launch_bounds__(256) void k0_prep(
    const float* __restrict__ wr, const float* __restrict__ wp,
    _Float16* __restrict__ wrAh, _Float16* __restrict__ wrAl,
    _Float16* __restrict__ wpH,
    float* __restrict__ icnG, float* __restrict__ featTail)
{
  const int tid = blockIdx.x * 256 + threadIdx.x;
  if (tid < 16384) {                          // wr[64][256] -> hi/lo A-frags
    const int j = tid & 7, l = (tid >> 3) & 63;
    const int kt = (tid >> 9) & 7, mt = tid >> 12;
    const int m = mt * 16 + (l & 15);
    const int k = kt * 32 + (l >> 4) * 8 + j;
    const float v = wr[m * CIN + k];
    const _Float16 h = (_Float16)v;
    wrAh[tid] = h;
    wrAl[tid] = (_Float16)(v - (float)h);
  } else if (tid < 16384 + COUT * CR) {       // wp[512][64] -> A-frags f16
    const int fi = tid - 16384;
    const int j = fi & 7, l = (fi >> 3) & 63;
    const int kt = (fi >> 9) & 1, ot = (fi >> 10) & 3, g = fi >> 12;
    const int o = g * 64 + ot * 16 + (l & 15);
    const int k = kt * 32 + (l >> 4) * 8 + j;
    wpH[fi] = (_Float16)wp[o * CR + k];
  } else {
    const int gi = tid - (16384 + COUT * CR);
    if (gi < CG)               icnG[gi] = 0.f;                         // head
    else if (gi < 2 * CG)      icnG[CG + NB * NPIX + (gi - CG)] = 0.f; // tail
    else if (gi < 2 * CG + FT) featTail[gi - 2 * CG] = 0.f;            // feat tail
  }
}

// ---------------------------------------------------------------------------
// K1 (MFMA): feat_h[b,px,ch] (f16, px-major) = sum_k wr[c][k]*x[b,k,px];
// icn (f32) = rsqrt(max(sum_c feat^2, 1e-16)). (unchanged from r15)
// ---------------------------------------------------------------------------
__global__ __launch_bounds__(512) void k1_reduce(
    const float* __restrict__ x,
    const _Float16* __restrict__ wrAh, const _Float16* __restrict__ wrAl,
    _Float16* __restrict__ feat_h, float* __restrict__ icn)
{
  const int blk = blockIdx.x;             // 512 = b(3b) | seg(6b)
  const int b = blk >> 6, seg = blk & 63;
  const int t = threadIdx.x, lane = t & 63;
  const int g = __builtin_amdgcn_readfirstlane((int)t >> 6);  // 0..7
  const int nt = g & 3, mth = g >> 2;
  const int col = lane & 15, krow = lane >> 4;

  const float* xb = x + (size_t)b * CIN * NPIX + seg * 64 + nt * 16 + col;

  f32x4 c0 = {0.f, 0.f, 0.f, 0.f};
  f32x4 c1 = {0.f, 0.f, 0.f, 0.f};

#pragma unroll
  for (int kt = 0; kt < 8; ++kt) {
    half8 Bh, Bl;
    const float* xk = xb + (size_t)(kt * 32 + krow * 8) * NPIX;
#pragma unroll
    for (int j = 0; j < 8; ++j) {
      const float v = xk[(size_t)j * NPIX];
      const _Float16 h = (_Float16)v;
      Bh[j] = h;
      Bl[j] = (_Float16)(v - (float)h);
    }
    const int fi0 = ((mth * 2 + 0) * 8 + kt) * 512 + lane * 8;
    const int fi1 = ((mth * 2 + 1) * 8 + kt) * 512 + lane * 8;
    const half8 Ah0 = *(const half8*)(wrAh + fi0);
    const half8 Al0 = *(const half8*)(wrAl + fi0);
    const half8 Ah1 = *(const half8*)(wrAh + fi1);
    const half8 Al1 = *(const half8*)(wrAl + fi1);
    c0 = __builtin_amdgcn_mfma_f32_16x16x32_f16(Ah0, Bh, c0, 0, 0, 0);
    c0 = __builtin_amdgcn_mfma_f32_16x16x32_f16(Ah0, Bl, c0, 0, 0, 0);
    c0 = __builtin_amdgcn_mfma_f32_16x16x32_f16(Al0, Bh, c0, 0, 0, 0);
    c1 = __builtin_amdgcn_mfma_f32_16x16x32_f16(Ah1, Bh, c1, 0, 0, 0);
    c1 = __builtin_amdgcn_mfma_f32_16x16x32_f16(Ah1, Bl, c1, 0, 0, 0);
    c1 = __builtin_amdgcn_mfma_f32_16x16x32_f16(Al1, Bh, c1, 0, 0, 0);
  }

  // C layout (HW-verified): col = lane&15, row = krow*4 + r (consecutive ch)
  const int px = seg * 64 + nt * 16 + col;
  _Float16* fb = feat_h + ((size_t)b * NPIX + px) * 64;
  const int ch0 = mth * 32 + krow * 4;
  half4 v0, v1;
  float p = 0.f;
#pragma unroll
  for (int r = 0; r < 4; ++r) {
    v0[r] = (_Float16)c0[r];
    v1[r] = (_Float16)c1[r];
    p = fmaf(c0[r], c0[r], p);
    p = fmaf(c1[r], c1[r], p);
  }
  *(half4*)(fb + ch0) = v0;
  *(half4*)(fb + ch0 + 16) = v1;

  p += __shfl_xor(p, 16);
  p += __shfl_xor(p, 32);

  __shared__ float cn[8][16];
  if (lane < 16) cn[g][lane] = p;
  __syncthreads();
  if (t < 64) {
    const int nt2 = t >> 4, c16 = t & 15;
    const float ss = cn[nt2][c16] + cn[nt2 + 4][c16];
    icn[b * NPIX + seg * 64 + t] = rsqrtf(fmaxf(ss, 1e-16f));
  }
}

// ---------------------------------------------------------------------------
// K23: fused attention+proj, HALF-ROW blocks for 4 blocks/CU barrier overlap.
// Block = (b, h, s): 32 px (cols s*32..s*32+31), 256 thr (4 waves).
// Grid = 1024 -> 4 blocks/CU, 16 waves/CU (r16 lesson: 1 block/CU lockstep
// kills barrier overlap; r15 had 2/CU; this gives 4-way).
// Staging: 40 px x 64 ch f16 tile (incl +-4 col halo) = 320 h8, contiguous;
// T14 split LOAD/WRITE, double-buffered, one barrier per neighbor row.
// Inner loop identical to r15 (ds_read_b128, 4x fdot2, dpp8_sum,
// sim=d*icnc*icnk, one-pass softmax exp(sim)<=e, pk_fma f16 dual acc).
// Phase B: corrH 32px x 64ch swizzled; wave wv -> out tiles T=wv*8..+8
// (A-frag index = T*2+kt from wpH, L2-hot), 2 px-tiles, 32 MFMA/wave.
// ---------------------------------------------------------------------------
__global__ __launch_bounds__(256, 4) void k23_fused(
    const _Float16* __restrict__ feat_h, const float* __restrict__ icn,
    const _Float16* __restrict__ wpH, float* __restrict__ out)
{
  const int blk = blockIdx.x;          // 1024
  const int b = blk & 7;               // XCD-aware: xcd = blk % 8 = b
  const int rest = blk >> 3;           // 0..127
  const int h = rest >> 1, s = rest & 1;
  const int t = threadIdx.x;
  const int lane = t & 63;
  const int wv = __builtin_amdgcn_readfirstlane((int)t >> 6);  // 0..3
  const int w = t >> 3;                // local px col 0..31
  const int cb = (t & 7) * 8;          // channel base for this lane
  const int wg = s * 32 + w;           // global col 0..63
  const int px = h * 64 + wg;
  const int gpx = b * NPIX + px;

  const float* cnb = icn + b * NPIX;

  __shared__ __align__(16) _Float16 fs[2][40][72];   // 11520 B, 144 B rows
  __shared__ float cnS[2][48];                       // 384 B
  __shared__ __align__(16) _Float16 corrH[2048];     // 4096 B: 32px x 64ch

  half8 rS0, rS1;
  float ricn = 0.f;

  auto LOAD = [&](int ar) {
    const long base = ((long)b * NPIX + ar * 64 + s * 32 - 4) * 64;  // f16 units
    rS0 = *(const half8*)(feat_h + base + (long)t * 8);   // 256 h8 contiguous
    if (t < 64) rS1 = *(const half8*)(feat_h + base + (long)(256 + t) * 8);
    if (t < 40) ricn = cnb[ar * 64 + s * 32 - 4 + t];
  };
  auto WRITE = [&](int bufi) {
    *(half8*)&fs[bufi][t >> 3][(t & 7) * 8] = rS0;
    if (t < 64) *(half8*)&fs[bufi][32 + (t >> 3)][(t & 7) * 8] = rS1;
    if (t < 40) cnS[bufi][t] = ricn;
  };

  // center features (f16, contiguous 16 B per lane)
  half2v fc2[4];
  {
    const half8 fcv = *(const half8*)(feat_h + ((size_t)b * NPIX + px) * 64 + cb);
#pragma unroll
    for (int i = 0; i < 4; ++i) { fc2[i][0] = fcv[2*i]; fc2[i][1] = fcv[2*i+1]; }
  }
  const float icnc = icn[gpx];

  half2v accA[4], accB[4];
#pragma unroll
  for (int i = 0; i < 4; ++i) {
    accA[i] = (half2v)(_Float16)0.f;
    accB[i] = (half2v)(_Float16)0.f;
  }

  const int lo = (h - 3 < 0) ? 0 : h - 3;
  const int hi = (h + 3 > 63) ? 63 : h + 3;
  float l = 7.0f * (float)(6 - (hi - lo));   // skipped rows: 7 x exp(0)

  LOAD(lo);
  WRITE(0);
  __syncthreads();

  int buf = 0;
  for (int ar = lo; ar <= hi; ++ar) {
    if (ar < hi) LOAD(ar + 1);               // issue early: hides under compute
#pragma unroll
    for (int dx = -3; dx <= 3; ++dx) {
      const int j = w + 4 + dx;              // 1..38 within 40-px tile
      const half8 nv = *(const half8*)&fs[buf][j][cb];
      half2v n0, n1, n2, n3;
      n0[0] = nv[0]; n0[1] = nv[1];
      n1[0] = nv[2]; n1[1] = nv[3];
      n2[0] = nv[4]; n2[1] = nv[5];
      n3[0] = nv[6]; n3[1] = nv[7];
      float d = 0.f;
      d = __builtin_amdgcn_fdot2(fc2[0], n0, d, false);
      d = __builtin_amdgcn_fdot2(fc2[1], n1, d, false);
      d = __builtin_amdgcn_fdot2(fc2[2], n2, d, false);
      d = __builtin_amdgcn_fdot2(fc2[3], n3, d, false);
      d = dpp8_sum(d);                 // 8-lane reduce, VALU-only
      const float icnk = cnS[buf][j];  // 0 on guard -> sim 0
      float sim = d * icnc * icnk;
      const bool valid = (unsigned)(wg + dx) < 64u;
      sim = valid ? sim : 0.f;         // select: NaN/Inf-safe
      const float p = __expf(sim);     // sim <= 1 -> p <= e
      l += p;
      const float pv = valid ? p : 0.f;
      const _Float16 ph = (_Float16)pv;
      half2v ph2; ph2[0] = ph; ph2[1] = ph;
      if (dx & 1) {
        accA[0] = ph2 * n0 + accA[0];
        accA[1] = ph2 * n1 + accA[1];
        accA[2] = ph2 * n2 + accA[2];
        accA[3] = ph2 * n3 + accA[3];
      } else {
        accB[0] = ph2 * n0 + accB[0];
        accB[1] = ph2 * n1 + accB[1];
        accB[2] = ph2 * n2 + accB[2];
        accB[3] = ph2 * n3 + accB[3];
      }
    }
    if (ar < hi) WRITE(buf ^ 1);             // vmcnt waits here, not earlier
    __syncthreads();
    buf ^= 1;
  }

  // combine f16 partials in f32, normalize, write f16 corrH (XOR-swizzled)
  {
    const float inv = __builtin_amdgcn_rcpf(l);
    half8 hv;
#pragma unroll
    for (int i = 0; i < 4; ++i) {
      const float a0 = (float)accA[i][0] + (float)accB[i][0];
      const float a1 = (float)accA[i][1] + (float)accB[i][1];
      hv[2*i]   = (_Float16)(a0 * inv);
      hv[2*i+1] = (_Float16)(a1 * inv);
    }
    const int wbyte = (w * 128 + (cb << 1)) ^ ((w & 7) << 4);
    *(half8*)((char*)corrH + wbyte) = hv;
  }
  __syncthreads();

  // ---- Phase B: wave wv -> out tiles T = wv*8 .. wv*8+7 (outs T*16..+16),
  // 2 px-tiles of 16. A-frag index = T*2+kt (wpH packing: ((g*4+ot)*2+kt)=T*2+kt).
  const char* cH = (const char*)corrH;
#pragma unroll
  for (int pt = 0; pt < 2; ++pt) {
    half8 Bf0, Bf1;
    {
      const int pxl = pt * 16 + (lane & 15);
      const int sw = (pxl & 7) << 4;
      const int rowb = pxl * 128 + ((lane >> 4) << 4);
      Bf0 = *(const half8*)(cH + (rowb ^ sw));
      Bf1 = *(const half8*)(cH + ((rowb + 64) ^ sw));
    }
#pragma unroll
    for (int ot = 0; ot < 8; ++ot) {
      const int T = wv * 8 + ot;
      f32x4 c = {0.f, 0.f, 0.f, 0.f};
      const half8 A0 = *(const half8*)(wpH + (size_t)(T * 2 + 0) * 512 + lane * 8);
      const half8 A1 = *(const half8*)(wpH + (size_t)(T * 2 + 1) * 512 + lane * 8);
      c = __builtin_amdgcn_mfma_f32_16x16x32_f16(A0, Bf0, c, 0, 0, 0);
      c = __builtin_amdgcn_mfma_f32_16x16x32_f16(A1, Bf1, c, 0, 0, 0);
      float* op = out + ((size_t)b * COUT + T * 16 + ((lane >> 4) << 2)) * NPIX
                      + h * 64 + s * 32 + pt * 16 + (lane & 15);
#pragma unroll
      for (int r = 0; r < 4; ++r) op[(size_t)r * NPIX] = c[r];
    }
  }
}

// ---------------------------------------------------------------------------
extern "C" void kernel_launch(void* const* d_in, const int* in_sizes, int n_in,
                              void* d_out, int out_size, void* d_ws, size_t ws_size,
                              hipStream_t stream)
{
  const float* x  = (const float*)d_in[0];
  const float* wr = (const float*)d_in[1];
  const float* wp = (const float*)d_in[2];
  float* out = (float*)d_out;

  // ws layout (float-slots):
  //   wrAh[8192] | wrAl[8192] | wpH[16384] |
  //   [CG] icn[8*4096] [CG] | feat_h[8*4096*64 f16 = 1M float-slots] | [FT]
  float* ws = (float*)d_ws;
  _Float16* wrAh  = (_Float16*)ws;
  _Float16* wrAl  = (_Float16*)(ws + 8192);
  _Float16* wpH   = (_Float16*)(ws + 16384);
  float* icnG     = ws + 32768;             // guarded region base
  float* icn      = icnG + CG;
  _Float16* feat_h = (_Float16*)(icn + NB * NPIX + CG);
  float* featTail = (float*)(feat_h + (size_t)NB * NPIX * 64);

  hipLaunchKernelGGL(k0_prep,   dim3(195),  dim3(256), 0, stream, wr, wp, wrAh, wrAl, wpH, icnG, featTail);
  hipLaunchKernelGGL(k1_reduce, dim3(512),  dim3(512), 0, stream, x, wrAh, wrAl, feat_h, icn);
  hipLaunchKernelGGL(k23_fused, dim3(1024), dim3(256), 0, stream, feat_h, icn, wpH, out);
}

// Round 19
// 37.968 us; speedup vs baseline: 1.1119x; 1.0480x over previous
//
#include <hip/hip_runtime.h>
#include <stdint.h>

#define NPIX 4096
#define CIN  256
#define CR   64
#define COUT 512
#define NB   8
#define CG   256     // icn guard floats each side (also covers feat_h head)
#define FT   128     // feat_h tail guard (floats; covers +4 px overhang)

typedef _Float16 half8 __attribute__((ext_vector_type(8)));
typedef _Float16 half4 __attribute__((ext_vector_type(4)));
typedef _Float16 half2v __attribute__((ext_vector_type(2)));
typedef float f32x4 __attribute__((ext_vector_type(4)));

// 8-lane sum (groups aligned to 8): quad_perm xor1, xor2, then row_half_mirror.
__device__ __forceinline__ float dpp8_sum(float d) {
  int y;
  y = __builtin_amdgcn_update_dpp(0, __float_as_int(d), 0xB1, 0xF, 0xF, true);
  d += __int_as_float(y);
  y = __builtin_amdgcn_update_dpp(0, __float_as_int(d), 0x4E, 0xF, 0xF, true);
  d += __int_as_float(y);
  y = __builtin_amdgcn_update_dpp(0, __float_as_int(d), 0x141, 0xF, 0xF, true);
  d += __int_as_float(y);
  return d;
}

// ---------------------------------------------------------------------------
// K0: pack w_reduce into hi/lo fp16 A-fragments (k1 MFMA), wp into fp16
// A-fragments (k23 phase B), zero guard zones. (unchanged from r15)
// ---------------------------------------------------------------------------
__global__ __launch_bounds__(256) void k0_prep(
    const float* __restrict__ wr, const float* __restrict__ wp,
    _Float16* __restrict__ wrAh, _Float16* __restrict__ wrAl,
    _Float16* __restrict__ wpH,
    float* __restrict__ icnG, float* __restrict__ featTail)
{
  const int tid = blockIdx.x * 256 + threadIdx.x;
  if (tid < 16384) {                          // wr[64][256] -> hi/lo A-frags
    const int j = tid & 7, l = (tid >> 3) & 63;
    const int kt = (tid >> 9) & 7, mt = tid >> 12;
    const int m = mt * 16 + (l & 15);
    const int k = kt * 32 + (l >> 4) * 8 + j;
    const float v = wr[m * CIN + k];
    const _Float16 h = (_Float16)v;
    wrAh[tid] = h;
    wrAl[tid] = (_Float16)(v - (float)h);
  } else if (tid < 16384 + COUT * CR) {       // wp[512][64] -> A-frags f16
    const int fi = tid - 16384;
    const int j = fi & 7, l = (fi >> 3) & 63;
    const int kt = (fi >> 9) & 1, ot = (fi >> 10) & 3, g = fi >> 12;
    const int o = g * 64 + ot * 16 + (l & 15);
    const int k = kt * 32 + (l >> 4) * 8 + j;
    wpH[fi] = (_Float16)wp[o * CR + k];
  } else {
    const int gi = tid - (16384 + COUT * CR);
    if (gi < CG)               icnG[gi] = 0.f;                         // head
    else if (gi < 2 * CG)      icnG[CG + NB * NPIX + (gi - CG)] = 0.f; // tail
    else if (gi < 2 * CG + FT) featTail[gi - 2 * CG] = 0.f;            // feat tail
  }
}

// ---------------------------------------------------------------------------
// K1 (MFMA): feat_h[b,px,ch] (f16, px-major) = sum_k wr[c][k]*x[b,k,px];
// icn (f32) = rsqrt(max(sum_c feat^2, 1e-16)). (unchanged from r15)
// ---------------------------------------------------------------------------
__global__ __launch_bounds__(512) void k1_reduce(
    const float* __restrict__ x,
    const _Float16* __restrict__ wrAh, const _Float16* __restrict__ wrAl,
    _Float16* __restrict__ feat_h, float* __restrict__ icn)
{
  const int blk = blockIdx.x;             // 512 = b(3b) | seg(6b)
  const int b = blk >> 6, seg = blk & 63;
  const int t = threadIdx.x, lane = t & 63;
  const int g = __builtin_amdgcn_readfirstlane((int)t >> 6);  // 0..7
  const int nt = g & 3, mth = g >> 2;
  const int col = lane & 15, krow = lane >> 4;

  const float* xb = x + (size_t)b * CIN * NPIX + seg * 64 + nt * 16 + col;

  f32x4 c0 = {0.f, 0.f, 0.f, 0.f};
  f32x4 c1 = {0.f, 0.f, 0.f, 0.f};

#pragma unroll
  for (int kt = 0; kt < 8; ++kt) {
    half8 Bh, Bl;
    const float* xk = xb + (size_t)(kt * 32 + krow * 8) * NPIX;
#pragma unroll
    for (int j = 0; j < 8; ++j) {
      const float v = xk[(size_t)j * NPIX];
      const _Float16 h = (_Float16)v;
      Bh[j] = h;
      Bl[j] = (_Float16)(v - (float)h);
    }
    const int fi0 = ((mth * 2 + 0) * 8 + kt) * 512 + lane * 8;
    const int fi1 = ((mth * 2 + 1) * 8 + kt) * 512 + lane * 8;
    const half8 Ah0 = *(const half8*)(wrAh + fi0);
    const half8 Al0 = *(const half8*)(wrAl + fi0);
    const half8 Ah1 = *(const half8*)(wrAh + fi1);
    const half8 Al1 = *(const half8*)(wrAl + fi1);
    c0 = __builtin_amdgcn_mfma_f32_16x16x32_f16(Ah0, Bh, c0, 0, 0, 0);
    c0 = __builtin_amdgcn_mfma_f32_16x16x32_f16(Ah0, Bl, c0, 0, 0, 0);
    c0 = __builtin_amdgcn_mfma_f32_16x16x32_f16(Al0, Bh, c0, 0, 0, 0);
    c1 = __builtin_amdgcn_mfma_f32_16x16x32_f16(Ah1, Bh, c1, 0, 0, 0);
    c1 = __builtin_amdgcn_mfma_f32_16x16x32_f16(Ah1, Bl, c1, 0, 0, 0);
    c1 = __builtin_amdgcn_mfma_f32_16x16x32_f16(Al1, Bh, c1, 0, 0, 0);
  }

  // C layout (HW-verified): col = lane&15, row = krow*4 + r (consecutive ch)
  const int px = seg * 64 + nt * 16 + col;
  _Float16* fb = feat_h + ((size_t)b * NPIX + px) * 64;
  const int ch0 = mth * 32 + krow * 4;
  half4 v0, v1;
  float p = 0.f;
#pragma unroll
  for (int r = 0; r < 4; ++r) {
    v0[r] = (_Float16)c0[r];
    v1[r] = (_Float16)c1[r];
    p = fmaf(c0[r], c0[r], p);
    p = fmaf(c1[r], c1[r], p);
  }
  *(half4*)(fb + ch0) = v0;
  *(half4*)(fb + ch0 + 16) = v1;

  p += __shfl_xor(p, 16);
  p += __shfl_xor(p, 32);

  __shared__ float cn[8][16];
  if (lane < 16) cn[g][lane] = p;
  __syncthreads();
  if (t < 64) {
    const int nt2 = t >> 4, c16 = t & 15;
    const float ss = cn[nt2][c16] + cn[nt2 + 4][c16];
    icn[b * NPIX + seg * 64 + t] = rsqrtf(fmaxf(ss, 1e-16f));
  }
}

// ---------------------------------------------------------------------------
// K23: fused attention+proj, half-row blocks (r17 structure) with:
//  (a) 2-deep staging pipeline: LOAD(ar+2) issued BEFORE compute(ar) -> two
//      compute phases + 2 barriers (~700cy) cover L2 latency; 2 LDS buffers,
//      two named register sets (P=row ar+1, N=row ar+2; explicit swap).
//  (b) phase B reordered: Bf (both px-tiles) hoisted to regs; ot-outer loop
//      loads each A-frag pair ONCE (halves L2 A-traffic) + 4 MFMA under
//      s_setprio(1).
// Block = (b, h, s): 32 px, 256 thr (4 waves), grid 1024 = 4 blocks/CU.
// Inner dx loop identical to r15/r17.
// ---------------------------------------------------------------------------
__global__ __launch_bounds__(256, 4) void k23_fused(
    const _Float16* __restrict__ feat_h, const float* __restrict__ icn,
    const _Float16* __restrict__ wpH, float* __restrict__ out)
{
  const int blk = blockIdx.x;          // 1024
  const int b = blk & 7;               // XCD-aware: xcd = blk % 8 = b
  const int rest = blk >> 3;           // 0..127
  const int h = rest >> 1, s = rest & 1;
  const int t = threadIdx.x;
  const int lane = t & 63;
  const int wv = __builtin_amdgcn_readfirstlane((int)t >> 6);  // 0..3
  const int w = t >> 3;                // local px col 0..31
  const int cb = (t & 7) * 8;          // channel base for this lane
  const int wg = s * 32 + w;           // global col 0..63
  const int px = h * 64 + wg;
  const int gpx = b * NPIX + px;

  const float* cnb = icn + b * NPIX;

  __shared__ __align__(16) _Float16 fs[2][40][72];   // 11520 B, 144 B rows
  __shared__ float cnS[2][48];                       // 384 B
  __shared__ __align__(16) _Float16 corrH[2048];     // 4096 B: 32px x 64ch

  // two staging register sets: P (next row to WRITE), N (row after, in flight)
  half8 pS0, pS1, nS0, nS1;
  float pIc = 0.f, nIc = 0.f;

  auto LOADP = [&](int ar) {
    const long base = ((long)b * NPIX + ar * 64 + s * 32 - 4) * 64;
    pS0 = *(const half8*)(feat_h + base + (long)t * 8);
    if (t < 64) pS1 = *(const half8*)(feat_h + base + (long)(256 + t) * 8);
    if (t < 40) pIc = cnb[ar * 64 + s * 32 - 4 + t];
  };
  auto LOADN = [&](int ar) {
    const long base = ((long)b * NPIX + ar * 64 + s * 32 - 4) * 64;
    nS0 = *(const half8*)(feat_h + base + (long)t * 8);
    if (t < 64) nS1 = *(const half8*)(feat_h + base + (long)(256 + t) * 8);
    if (t < 40) nIc = cnb[ar * 64 + s * 32 - 4 + t];
  };
  auto WRITEP = [&](int bufi) {
    *(half8*)&fs[bufi][t >> 3][(t & 7) * 8] = pS0;
    if (t < 64) *(half8*)&fs[bufi][32 + (t >> 3)][(t & 7) * 8] = pS1;
    if (t < 40) cnS[bufi][t] = pIc;
  };

  // center features (f16, contiguous 16 B per lane)
  half2v fc2[4];
  {
    const half8 fcv = *(const half8*)(feat_h + ((size_t)b * NPIX + px) * 64 + cb);
#pragma unroll
    for (int i = 0; i < 4; ++i) { fc2[i][0] = fcv[2*i]; fc2[i][1] = fcv[2*i+1]; }
  }
  const float icnc = icn[gpx];

  half2v accA[4], accB[4];
#pragma unroll
  for (int i = 0; i < 4; ++i) {
    accA[i] = (half2v)(_Float16)0.f;
    accB[i] = (half2v)(_Float16)0.f;
  }

  const int lo = (h - 3 < 0) ? 0 : h - 3;
  const int hi = (h + 3 > 63) ? 63 : h + 3;
  float l = 7.0f * (float)(6 - (hi - lo));   // skipped rows: 7 x exp(0)

  // prologue: fs[0] <- row lo; P <- row lo+1 (window always >= 4 rows)
  LOADP(lo);
  WRITEP(0);
  LOADP(lo + 1);
  __syncthreads();

  int buf = 0;
  for (int ar = lo; ar <= hi; ++ar) {
    if (ar + 2 <= hi) LOADN(ar + 2);         // 2-deep: lands 2 phases later
#pragma unroll
    for (int dx = -3; dx <= 3; ++dx) {
      const int j = w + 4 + dx;              // 1..38 within 40-px tile
      const half8 nv = *(const half8*)&fs[buf][j][cb];
      half2v n0, n1, n2, n3;
      n0[0] = nv[0]; n0[1] = nv[1];
      n1[0] = nv[2]; n1[1] = nv[3];
      n2[0] = nv[4]; n2[1] = nv[5];
      n3[0] = nv[6]; n3[1] = nv[7];
      float d = 0.f;
      d = __builtin_amdgcn_fdot2(fc2[0], n0, d, false);
      d = __builtin_amdgcn_fdot2(fc2[1], n1, d, false);
      d = __builtin_amdgcn_fdot2(fc2[2], n2, d, false);
      d = __builtin_amdgcn_fdot2(fc2[3], n3, d, false);
      d = dpp8_sum(d);                 // 8-lane reduce, VALU-only
      const float icnk = cnS[buf][j];  // 0 on guard -> sim 0
      float sim = d * icnc * icnk;
      const bool valid = (unsigned)(wg + dx) < 64u;
      sim = valid ? sim : 0.f;         // select: NaN/Inf-safe
      const float p = __expf(sim);     // sim <= 1 -> p <= e
      l += p;
      const float pv = valid ? p : 0.f;
      const _Float16 ph = (_Float16)pv;
      half2v ph2; ph2[0] = ph; ph2[1] = ph;
      if (dx & 1) {
        accA[0] = ph2 * n0 + accA[0];
        accA[1] = ph2 * n1 + accA[1];
        accA[2] = ph2 * n2 + accA[2];
        accA[3] = ph2 * n3 + accA[3];
      } else {
        accB[0] = ph2 * n0 + accB[0];
        accB[1] = ph2 * n1 + accB[1];
        accB[2] = ph2 * n2 + accB[2];
        accB[3] = ph2 * n3 + accB[3];
      }
    }
    if (ar + 1 <= hi) WRITEP(buf ^ 1);       // P = row ar+1 (loaded >=1 phase ago)
    __syncthreads();
    buf ^= 1;
    pS0 = nS0; pS1 = nS1; pIc = nIc;         // P <- N (explicit, rule-#20 safe)
  }

  // combine f16 partials in f32, normalize, write f16 corrH (XOR-swizzled)
  {
    const float inv = __builtin_amdgcn_rcpf(l);
    half8 hv;
#pragma unroll
    for (int i = 0; i < 4; ++i) {
      const float a0 = (float)accA[i][0] + (float)accB[i][0];
      const float a1 = (float)accA[i][1] + (float)accB[i][1];
      hv[2*i]   = (_Float16)(a0 * inv);
      hv[2*i+1] = (_Float16)(a1 * inv);
    }
    const int wbyte = (w * 128 + (cb << 1)) ^ ((w & 7) << 4);
    *(half8*)((char*)corrH + wbyte) = hv;
  }
  __syncthreads();

  // ---- Phase B: Bf hoisted; ot-outer loads each A pair once; 4 MFMA/ot.
  const char* cH = (const char*)corrH;
  half8 Bf00, Bf01, Bf10, Bf11;
  {
    const int pxl0 = (lane & 15);
    const int sw0 = (pxl0 & 7) << 4;
    const int rowb0 = pxl0 * 128 + ((lane >> 4) << 4);
    Bf00 = *(const half8*)(cH + (rowb0 ^ sw0));
    Bf01 = *(const half8*)(cH + ((rowb0 + 64) ^ sw0));
    const int pxl1 = 16 + (lane & 15);
    const int sw1 = (pxl1 & 7) << 4;
    const int rowb1 = pxl1 * 128 + ((lane >> 4) << 4);
    Bf10 = *(const half8*)(cH + (rowb1 ^ sw1));
    Bf11 = *(const half8*)(cH + ((rowb1 + 64) ^ sw1));
  }
#pragma unroll
  for (int ot = 0; ot < 8; ++ot) {
    const int T = wv * 8 + ot;
    const half8 A0 = *(const half8*)(wpH + (size_t)(T * 2 + 0) * 512 + lane * 8);
    const half8 A1 = *(const half8*)(wpH + (size_t)(T * 2 + 1) * 512 + lane * 8);
    f32x4 c0 = {0.f, 0.f, 0.f, 0.f};
    f32x4 c1 = {0.f, 0.f, 0.f, 0.f};
    __builtin_amdgcn_s_setprio(1);
    c0 = __builtin_amdgcn_mfma_f32_16x16x32_f16(A0, Bf00, c0, 0, 0, 0);
    c0 = __builtin_amdgcn_mfma_f32_16x16x32_f16(A1, Bf01, c0, 0, 0, 0);
    c1 = __builtin_amdgcn_mfma_f32_16x16x32_f16(A0, Bf10, c1, 0, 0, 0);
    c1 = __builtin_amdgcn_mfma_f32_16x16x32_f16(A1, Bf11, c1, 0, 0, 0);
    __builtin_amdgcn_s_setprio(0);
    float* op0 = out + ((size_t)b * COUT + T * 16 + ((lane >> 4) << 2)) * NPIX
                     + h * 64 + s * 32 + (lane & 15);
#pragma unroll
    for (int r = 0; r < 4; ++r) {
      op0[(size_t)r * NPIX] = c0[r];
      op0[(size_t)r * NPIX + 16] = c1[r];
    }
  }
}

// ---------------------------------------------------------------------------
extern "C" void kernel_launch(void* const* d_in, const int* in_sizes, int n_in,
                              void* d_out, int out_size, void* d_ws, size_t ws_size,
                              hipStream_t stream)
{
  const float* x  = (const float*)d_in[0];
  const float* wr = (const float*)d_in[1];
  const float* wp = (const float*)d_in[2];
  float* out = (float*)d_out;

  // ws layout (float-slots):
  //   wrAh[8192] | wrAl[8192] | wpH[16384] |
  //   [CG] icn[8*4096] [CG] | feat_h[8*4096*64 f16 = 1M float-slots] | [FT]
  float* ws = (float*)d_ws;
  _Float16* wrAh  = (_Float16*)ws;
  _Float16* wrAl  = (_Float16*)(ws + 8192);
  _Float16* wpH   = (_Float16*)(ws + 16384);
  float* icnG     = ws + 32768;             // guarded region base
  float* icn      = icnG + CG;
  _Float16* feat_h = (_Float16*)(icn + NB * NPIX + CG);
  float* featTail = (float*)(feat_h + (size_t)NB * NPIX * 64);

  hipLaunchKernelGGL(k0_prep,   dim3(195),  dim3(256), 0, stream, wr, wp, wrAh, wrAl, wpH, icnG, featTail);
  hipLaunchKernelGGL(k1_reduce, dim3(512),  dim3(512), 0, stream, x, wrAh, wrAl, feat_h, icn);
  hipLaunchKernelGGL(k23_fused, dim3(1024), dim3(256), 0, stream, feat_h, icn, wpH, out);
}

// Round 20
// 37.572 us; speedup vs baseline: 1.1236x; 1.0105x over previous
//
#include <hip/hip_runtime.h>
#include <stdint.h>

#define NPIX 4096
#define CIN  256
#define CR   64
#define COUT 512
#define NB   8
#define CG   256     // icn guard floats each side (also covers feat_h head)
#define FT   128     // feat_h tail guard (floats; covers +4 px overhang)

typedef _Float16 half8 __attribute__((ext_vector_type(8)));
typedef _Float16 half4 __attribute__((ext_vector_type(4)));
typedef _Float16 half2v __attribute__((ext_vector_type(2)));
typedef float f32x4 __attribute__((ext_vector_type(4)));

// 8-lane sum (groups aligned to 8): quad_perm xor1, xor2, then row_half_mirror.
__device__ __forceinline__ float dpp8_sum(float d) {
  int y;
  y = __builtin_amdgcn_update_dpp(0, __float_as_int(d), 0xB1, 0xF, 0xF, true);
  d += __int_as_float(y);
  y = __builtin_amdgcn_update_dpp(0, __float_as_int(d), 0x4E, 0xF, 0xF, true);
  d += __int_as_float(y);
  y = __builtin_amdgcn_update_dpp(0, __float_as_int(d), 0x141, 0xF, 0xF, true);
  d += __int_as_float(y);
  return d;
}

// ---------------------------------------------------------------------------
// K0: pack w_reduce into hi/lo fp16 A-fragments (k1 MFMA), wp into fp16
// A-fragments (k23 phase B), zero guard zones. (unchanged from r15)
// ---------------------------------------------------------------------------
__global__ __launch_bounds__(256) void k0_prep(
    const float* __restrict__ wr, const float* __restrict__ wp,
    _Float16* __restrict__ wrAh, _Float16* __restrict__ wrAl,
    _Float16* __restrict__ wpH,
    float* __restrict__ icnG, float* __restrict__ featTail)
{
  const int tid = blockIdx.x * 256 + threadIdx.x;
  if (tid < 16384) {                          // wr[64][256] -> hi/lo A-frags
    const int j = tid & 7, l = (tid >> 3) & 63;
    const int kt = (tid >> 9) & 7, mt = tid >> 12;
    const int m = mt * 16 + (l & 15);
    const int k = kt * 32 + (l >> 4) * 8 + j;
    const float v = wr[m * CIN + k];
    const _Float16 h = (_Float16)v;
    wrAh[tid] = h;
    wrAl[tid] = (_Float16)(v - (float)h);
  } else if (tid < 16384 + COUT * CR) {       // wp[512][64] -> A-frags f16
    const int fi = tid - 16384;
    const int j = fi & 7, l = (fi >> 3) & 63;
    const int kt = (fi >> 9) & 1, ot = (fi >> 10) & 3, g = fi >> 12;
    const int o = g * 64 + ot * 16 + (l & 15);
    const int k = kt * 32 + (l >> 4) * 8 + j;
    wpH[fi] = (_Float16)wp[o * CR + k];
  } else {
    const int gi = tid - (16384 + COUT * CR);
    if (gi < CG)               icnG[gi] = 0.f;                         // head
    else if (gi < 2 * CG)      icnG[CG + NB * NPIX + (gi - CG)] = 0.f; // tail
    else if (gi < 2 * CG + FT) featTail[gi - 2 * CG] = 0.f;            // feat tail
  }
}

// ---------------------------------------------------------------------------
// K1 (MFMA): feat_h[b,px,ch] (f16, px-major) = sum_k wr[c][k]*x[b,k,px];
// icn (f32) = rsqrt(max(sum_c feat^2, 1e-16)). (unchanged from r15)
// ---------------------------------------------------------------------------
__global__ __launch_bounds__(512) void k1_reduce(
    const float* __restrict__ x,
    const _Float16* __restrict__ wrAh, const _Float16* __restrict__ wrAl,
    _Float16* __restrict__ feat_h, float* __restrict__ icn)
{
  const int blk = blockIdx.x;             // 512 = b(3b) | seg(6b)
  const int b = blk >> 6, seg = blk & 63;
  const int t = threadIdx.x, lane = t & 63;
  const int g = __builtin_amdgcn_readfirstlane((int)t >> 6);  // 0..7
  const int nt = g & 3, mth = g >> 2;
  const int col = lane & 15, krow = lane >> 4;

  const float* xb = x + (size_t)b * CIN * NPIX + seg * 64 + nt * 16 + col;

  f32x4 c0 = {0.f, 0.f, 0.f, 0.f};
  f32x4 c1 = {0.f, 0.f, 0.f, 0.f};

#pragma unroll
  for (int kt = 0; kt < 8; ++kt) {
    half8 Bh, Bl;
    const float* xk = xb + (size_t)(kt * 32 + krow * 8) * NPIX;
#pragma unroll
    for (int j = 0; j < 8; ++j) {
      const float v = xk[(size_t)j * NPIX];
      const _Float16 h = (_Float16)v;
      Bh[j] = h;
      Bl[j] = (_Float16)(v - (float)h);
    }
    const int fi0 = ((mth * 2 + 0) * 8 + kt) * 512 + lane * 8;
    const int fi1 = ((mth * 2 + 1) * 8 + kt) * 512 + lane * 8;
    const half8 Ah0 = *(const half8*)(wrAh + fi0);
    const half8 Al0 = *(const half8*)(wrAl + fi0);
    const half8 Ah1 = *(const half8*)(wrAh + fi1);
    const half8 Al1 = *(const half8*)(wrAl + fi1);
    c0 = __builtin_amdgcn_mfma_f32_16x16x32_f16(Ah0, Bh, c0, 0, 0, 0);
    c0 = __builtin_amdgcn_mfma_f32_16x16x32_f16(Ah0, Bl, c0, 0, 0, 0);
    c0 = __builtin_amdgcn_mfma_f32_16x16x32_f16(Al0, Bh, c0, 0, 0, 0);
    c1 = __builtin_amdgcn_mfma_f32_16x16x32_f16(Ah1, Bh, c1, 0, 0, 0);
    c1 = __builtin_amdgcn_mfma_f32_16x16x32_f16(Ah1, Bl, c1, 0, 0, 0);
    c1 = __builtin_amdgcn_mfma_f32_16x16x32_f16(Al1, Bh, c1, 0, 0, 0);
  }

  // C layout (HW-verified): col = lane&15, row = krow*4 + r (consecutive ch)
  const int px = seg * 64 + nt * 16 + col;
  _Float16* fb = feat_h + ((size_t)b * NPIX + px) * 64;
  const int ch0 = mth * 32 + krow * 4;
  half4 v0, v1;
  float p = 0.f;
#pragma unroll
  for (int r = 0; r < 4; ++r) {
    v0[r] = (_Float16)c0[r];
    v1[r] = (_Float16)c1[r];
    p = fmaf(c0[r], c0[r], p);
    p = fmaf(c1[r], c1[r], p);
  }
  *(half4*)(fb + ch0) = v0;
  *(half4*)(fb + ch0 + 16) = v1;

  p += __shfl_xor(p, 16);
  p += __shfl_xor(p, 32);

  __shared__ float cn[8][16];
  if (lane < 16) cn[g][lane] = p;
  __syncthreads();
  if (t < 64) {
    const int nt2 = t >> 4, c16 = t & 15;
    const float ss = cn[nt2][c16] + cn[nt2 + 4][c16];
    icn[b * NPIX + seg * 64 + t] = rsqrtf(fmaxf(ss, 1e-16f));
  }
}

// ---------------------------------------------------------------------------
// K23: fused attention+proj, half-row blocks (r17/r18 structure) with
// TWO-ROW LDS PHASES: stage rows in groups of 2 (fs[2][2][40][72], 23 KB),
// compute 14 dx-neighbors per phase -> barriers drop 9 -> 6 per block and
// each phase (~560cy compute) covers L2 latency with single-depth group
// prefetch (LOADG(gs+2) issued before computing group gs).
// Block = (b, h, s): 32 px, 256 thr (4 waves), grid 1024 = 4 blocks/CU.
// Inner dx loop and phase B (hoisted Bf, ot-outer A loads, setprio)
// unchanged from r18. Group's 2nd row loaded/computed only if <= hi;
// stale registers written to unused LDS slots are finite.
// ---------------------------------------------------------------------------
__global__ __launch_bounds__(256, 4) void k23_fused(
    const _Float16* __restrict__ feat_h, const float* __restrict__ icn,
    const _Float16* __restrict__ wpH, float* __restrict__ out)
{
  const int blk = blockIdx.x;          // 1024
  const int b = blk & 7;               // XCD-aware: xcd = blk % 8 = b
  const int rest = blk >> 3;           // 0..127
  const int h = rest >> 1, s = rest & 1;
  const int t = threadIdx.x;
  const int lane = t & 63;
  const int wv = __builtin_amdgcn_readfirstlane((int)t >> 6);  // 0..3
  const int w = t >> 3;                // local px col 0..31
  const int cb = (t & 7) * 8;          // channel base for this lane
  const int wg = s * 32 + w;           // global col 0..63
  const int px = h * 64 + wg;
  const int gpx = b * NPIX + px;

  const float* cnb = icn + b * NPIX;

  __shared__ __align__(16) _Float16 fs[2][2][40][72];  // 23040 B
  __shared__ float cnS[2][2][48];                      // 768 B
  __shared__ __align__(16) _Float16 corrH[2048];       // 4096 B: 32px x 64ch

  // staging registers for one 2-row group (row A = gs, row B = gs+1)
  half8 sA0 = (half8)(_Float16)0.f, sA1 = (half8)(_Float16)0.f;
  half8 sB0 = (half8)(_Float16)0.f, sB1 = (half8)(_Float16)0.f;
  float icA = 0.f, icB = 0.f;

  const int lo = (h - 3 < 0) ? 0 : h - 3;
  const int hi = (h + 3 > 63) ? 63 : h + 3;

  auto LOADG = [&](int gs) {
    {
      const long base = ((long)b * NPIX + gs * 64 + s * 32 - 4) * 64;
      sA0 = *(const half8*)(feat_h + base + (long)t * 8);
      if (t < 64) sA1 = *(const half8*)(feat_h + base + (long)(256 + t) * 8);
      if (t < 40) icA = cnb[gs * 64 + s * 32 - 4 + t];
    }
    if (gs + 1 <= hi) {
      const long base = ((long)b * NPIX + (gs + 1) * 64 + s * 32 - 4) * 64;
      sB0 = *(const half8*)(feat_h + base + (long)t * 8);
      if (t < 64) sB1 = *(const half8*)(feat_h + base + (long)(256 + t) * 8);
      if (t < 40) icB = cnb[(gs + 1) * 64 + s * 32 - 4 + t];
    }
  };
  auto WRITEG = [&](int bufi) {
    *(half8*)&fs[bufi][0][t >> 3][(t & 7) * 8] = sA0;
    if (t < 64) *(half8*)&fs[bufi][0][32 + (t >> 3)][(t & 7) * 8] = sA1;
    if (t < 40) cnS[bufi][0][t] = icA;
    *(half8*)&fs[bufi][1][t >> 3][(t & 7) * 8] = sB0;   // stale ok: guarded
    if (t < 64) *(half8*)&fs[bufi][1][32 + (t >> 3)][(t & 7) * 8] = sB1;
    if (t < 40) cnS[bufi][1][t] = icB;
  };

  // center features (f16, contiguous 16 B per lane)
  half2v fc2[4];
  {
    const half8 fcv = *(const half8*)(feat_h + ((size_t)b * NPIX + px) * 64 + cb);
#pragma unroll
    for (int i = 0; i < 4; ++i) { fc2[i][0] = fcv[2*i]; fc2[i][1] = fcv[2*i+1]; }
  }
  const float icnc = icn[gpx];

  half2v accA[4], accB[4];
#pragma unroll
  for (int i = 0; i < 4; ++i) {
    accA[i] = (half2v)(_Float16)0.f;
    accB[i] = (half2v)(_Float16)0.f;
  }

  float l = 7.0f * (float)(6 - (hi - lo));   // skipped rows: 7 x exp(0)

  LOADG(lo);
  WRITEG(0);
  __syncthreads();

  int buf = 0;
  for (int gs = lo; gs <= hi; gs += 2) {
    if (gs + 2 <= hi) LOADG(gs + 2);         // group prefetch (~560cy cover)
    for (int q = 0; q < 2; ++q) {
      const int ar = gs + q;
      if (ar > hi) break;                    // block-uniform
#pragma unroll
      for (int dx = -3; dx <= 3; ++dx) {
        const int j = w + 4 + dx;            // 1..38 within 40-px tile
        const half8 nv = *(const half8*)&fs[buf][q][j][cb];
        half2v n0, n1, n2, n3;
        n0[0] = nv[0]; n0[1] = nv[1];
        n1[0] = nv[2]; n1[1] = nv[3];
        n2[0] = nv[4]; n2[1] = nv[5];
        n3[0] = nv[6]; n3[1] = nv[7];
        float d = 0.f;
        d = __builtin_amdgcn_fdot2(fc2[0], n0, d, false);
        d = __builtin_amdgcn_fdot2(fc2[1], n1, d, false);
        d = __builtin_amdgcn_fdot2(fc2[2], n2, d, false);
        d = __builtin_amdgcn_fdot2(fc2[3], n3, d, false);
        d = dpp8_sum(d);                 // 8-lane reduce, VALU-only
        const float icnk = cnS[buf][q][j];   // 0 on guard -> sim 0
        float sim = d * icnc * icnk;
        const bool valid = (unsigned)(wg + dx) < 64u;
        sim = valid ? sim : 0.f;         // select: NaN/Inf-safe
        const float p = __expf(sim);     // sim <= 1 -> p <= e
        l += p;
        const float pv = valid ? p : 0.f;
        const _Float16 ph = (_Float16)pv;
        half2v ph2; ph2[0] = ph; ph2[1] = ph;
        if (dx & 1) {
          accA[0] = ph2 * n0 + accA[0];
          accA[1] = ph2 * n1 + accA[1];
          accA[2] = ph2 * n2 + accA[2];
          accA[3] = ph2 * n3 + accA[3];
        } else {
          accB[0] = ph2 * n0 + accB[0];
          accB[1] = ph2 * n1 + accB[1];
          accB[2] = ph2 * n2 + accB[2];
          accB[3] = ph2 * n3 + accB[3];
        }
      }
    }
    if (gs + 2 <= hi) WRITEG(buf ^ 1);
    __syncthreads();
    buf ^= 1;
  }

  // combine f16 partials in f32, normalize, write f16 corrH (XOR-swizzled)
  {
    const float inv = __builtin_amdgcn_rcpf(l);
    half8 hv;
#pragma unroll
    for (int i = 0; i < 4; ++i) {
      const float a0 = (float)accA[i][0] + (float)accB[i][0];
      const float a1 = (float)accA[i][1] + (float)accB[i][1];
      hv[2*i]   = (_Float16)(a0 * inv);
      hv[2*i+1] = (_Float16)(a1 * inv);
    }
    const int wbyte = (w * 128 + (cb << 1)) ^ ((w & 7) << 4);
    *(half8*)((char*)corrH + wbyte) = hv;
  }
  __syncthreads();

  // ---- Phase B: Bf hoisted; ot-outer loads each A pair once; 4 MFMA/ot.
  const char* cH = (const char*)corrH;
  half8 Bf00, Bf01, Bf10, Bf11;
  {
    const int pxl0 = (lane & 15);
    const int sw0 = (pxl0 & 7) << 4;
    const int rowb0 = pxl0 * 128 + ((lane >> 4) << 4);
    Bf00 = *(const half8*)(cH + (rowb0 ^ sw0));
    Bf01 = *(const half8*)(cH + ((rowb0 + 64) ^ sw0));
    const int pxl1 = 16 + (lane & 15);
    const int sw1 = (pxl1 & 7) << 4;
    const int rowb1 = pxl1 * 128 + ((lane >> 4) << 4);
    Bf10 = *(const half8*)(cH + (rowb1 ^ sw1));
    Bf11 = *(const half8*)(cH + ((rowb1 + 64) ^ sw1));
  }
#pragma unroll
  for (int ot = 0; ot < 8; ++ot) {
    const int T = wv * 8 + ot;
    const half8 A0 = *(const half8*)(wpH + (size_t)(T * 2 + 0) * 512 + lane * 8);
    const half8 A1 = *(const half8*)(wpH + (size_t)(T * 2 + 1) * 512 + lane * 8);
    f32x4 c0 = {0.f, 0.f, 0.f, 0.f};
    f32x4 c1 = {0.f, 0.f, 0.f, 0.f};
    __builtin_amdgcn_s_setprio(1);
    c0 = __builtin_amdgcn_mfma_f32_16x16x32_f16(A0, Bf00, c0, 0, 0, 0);
    c0 = __builtin_amdgcn_mfma_f32_16x16x32_f16(A1, Bf01, c0, 0, 0, 0);
    c1 = __builtin_amdgcn_mfma_f32_16x16x32_f16(A0, Bf10, c1, 0, 0, 0);
    c1 = __builtin_amdgcn_mfma_f32_16x16x32_f16(A1, Bf11, c1, 0, 0, 0);
    __builtin_amdgcn_s_setprio(0);
    float* op0 = out + ((size_t)b * COUT + T * 16 + ((lane >> 4) << 2)) * NPIX
                     + h * 64 + s * 32 + (lane & 15);
#pragma unroll
    for (int r = 0; r < 4; ++r) {
      op0[(size_t)r * NPIX] = c0[r];
      op0[(size_t)r * NPIX + 16] = c1[r];
    }
  }
}

// ---------------------------------------------------------------------------
extern "C" void kernel_launch(void* const* d_in, const int* in_sizes, int n_in,
                              void* d_out, int out_size, void* d_ws, size_t ws_size,
                              hipStream_t stream)
{
  const float* x  = (const float*)d_in[0];
  const float* wr = (const float*)d_in[1];
  const float* wp = (const float*)d_in[2];
  float* out = (float*)d_out;

  // ws layout (float-slots):
  //   wrAh[8192] | wrAl[8192] | wpH[16384] |
  //   [CG] icn[8*4096] [CG] | feat_h[8*4096*64 f16 = 1M float-slots] | [FT]
  float* ws = (float*)d_ws;
  _Float16* wrAh  = (_Float16*)ws;
  _Float16* wrAl  = (_Float16*)(ws + 8192);
  _Float16* wpH   = (_Float16*)(ws + 16384);
  float* icnG     = ws + 32768;             // guarded region base
  float* icn      = icnG + CG;
  _Float16* feat_h = (_Float16*)(icn + NB * NPIX + CG);
  float* featTail = (float*)(feat_h + (size_t)NB * NPIX * 64);

  hipLaunchKernelGGL(k0_prep,   dim3(195),  dim3(256), 0, stream, wr, wp, wrAh, wrAl, wpH, icnG, featTail);
  hipLaunchKernelGGL(k1_reduce, dim3(512),  dim3(512), 0, stream, x, wrAh, wrAl, feat_h, icn);
  hipLaunchKernelGGL(k23_fused, dim3(1024), dim3(256), 0, stream, feat_h, icn, wpH, out);
}